// Round 6
// baseline (39.156 us; speedup 1.0000x reference)
//
#include <hip/hip_runtime.h>
#include <math.h>
#include <float.h>

namespace {

constexpr int kB  = 32;
constexpr int kT  = 4096;
constexpr int kTQ = 64;
constexpr int kD  = 256;
constexpr int kS  = 64;

// FTZ exp: flush subnormal results to zero, matching an XLA-style f32
// pipeline (exp output below FLT_MIN -> 0; downstream arithmetic never
// sees denormals).
__device__ __forceinline__ float exp_ftz(float x) {
  const float y = expf(x);
  return (y < 1.17549435e-38f) ? 0.f : y;
}

// K1: scores[b,t] = dot(doc[b,t,:], max_tq q[b,tq,:]).
// 512 threads = 8 waves; 64 tokens per block; 2048 blocks (64 per batch).
// qp recomputed per block into LDS (no workspace); f64 accumulation for the
// dot (accurate f32 result; exp cliffs are insensitive to 1e-4 score noise).
__global__ __launch_bounds__(512) void score_kernel(const float* __restrict__ doc,
                                                    const float* __restrict__ q,
                                                    float* __restrict__ scores) {
  __shared__ float qpl[2 * kD];
  const int tid = threadIdx.x;
  const int blk = blockIdx.x;
  const int b = blk >> 6;  // 64 blocks per batch

  // query max-pool, split over two thread-groups (g = tq-half)
  {
    const int d = tid & 255;
    const int g = tid >> 8;  // 0 or 1
    const float* base = q + ((size_t)b * kTQ + g * 32) * kD + d;
    float m = base[0];
#pragma unroll
    for (int tq = 1; tq < 32; ++tq) m = fmaxf(m, base[tq * kD]);
    qpl[g * kD + d] = m;
  }
  __syncthreads();

  const int wave = tid >> 6;
  const int lane = tid & 63;
  const float4 qa = reinterpret_cast<const float4*>(qpl)[lane];
  const float4 qb = reinterpret_cast<const float4*>(qpl)[64 + lane];
  float4 qv;
  qv.x = fmaxf(qa.x, qb.x);
  qv.y = fmaxf(qa.y, qb.y);
  qv.z = fmaxf(qa.z, qb.z);
  qv.w = fmaxf(qa.w, qb.w);

  const int tok0 = blk * 64 + wave * 8;  // global token index (all same b)
  const float* dbase = doc + (size_t)tok0 * kD + lane * 4;
#pragma unroll
  for (int i = 0; i < 8; ++i) {
    const float4 dv = *reinterpret_cast<const float4*>(dbase + (size_t)i * kD);
    double s = (double)dv.x * qv.x + (double)dv.y * qv.y +
               (double)dv.z * qv.z + (double)dv.w * qv.w;
#pragma unroll
    for (int off = 32; off >= 1; off >>= 1) s += __shfl_xor(s, off, 64);
    if (lane == 0) scores[tok0 + i] = (float)s;
  }
}

// K2: faithful FTZ-f32 softmax_mask + adjust_scores per row.  One block per b.
// Reads row b of `scores` (staged in d_out) then overwrites it with the final
// output (block-local read-then-write; safe).
__global__ __launch_bounds__(256) void finish_kernel(const float* __restrict__ scores,
                                                     const float* __restrict__ mask,
                                                     const float* __restrict__ sscore,
                                                     float* __restrict__ out) {
  const int b = blockIdx.x;
  const int tid = threadIdx.x;
  const int lane = tid & 63;
  const int wv = tid >> 6;

  __shared__ float prob_s[kT];  // 16 KB
  __shared__ float redm[4], redd[4], redt[4];
  __shared__ float sscale[kS];

  const float* sc = scores + (size_t)b * kT;
  const float* mk = mask + (size_t)b * kT;

  // pass 1: masked = scores*mask; gmax = max over ALL slots (incl. zeros)
  float ma[16], m[16];
  float lmax = -INFINITY;
#pragma unroll
  for (int j = 0; j < 16; ++j) {
    const int t = tid + 256 * j;
    const float s = sc[t];
    const float mm = mk[t];
    m[j] = mm;
    ma[j] = s * mm;
    lmax = fmaxf(lmax, ma[j]);
  }
#pragma unroll
  for (int off = 32; off >= 1; off >>= 1) lmax = fmaxf(lmax, __shfl_xor(lmax, off, 64));
  if (lane == 0) redm[wv] = lmax;
  __syncthreads();
  const float gmax = fmaxf(fmaxf(redm[0], redm[1]), fmaxf(redm[2], redm[3]));

  // pass 2: shifted = (masked - gmax)*mask; denom = sum(exp_ftz(shifted)*mask)
  float sh[16];
  float lsum = 0.f;
#pragma unroll
  for (int j = 0; j < 16; ++j) {
    sh[j] = (ma[j] - gmax) * m[j];
    lsum += exp_ftz(sh[j]) * m[j];
  }
  float ws = lsum;
#pragma unroll
  for (int off = 32; off >= 1; off >>= 1) ws += __shfl_xor(ws, off, 64);
  if (lane == 0) redd[wv] = ws;
  __syncthreads();
  const float denom = (redd[0] + redd[1]) + (redd[2] + redd[3]);
  const float logden = logf(denom);

  // pass 3: probs = exp_ftz((shifted - logdenom)*mask)*mask  -> LDS
#pragma unroll
  for (int j = 0; j < 16; ++j) {
    const int t = tid + 256 * j;
    const float x = (sh[j] - logden) * m[j];
    prob_s[t] = exp_ftz(x) * m[j];
  }
  __syncthreads();

  // span scales with FTZ semantics: span_sum (t-order, f32),
  // sm = span_sum/64 flushed to 0 if subnormal, nz = (sm != 0),
  // scale = nz ? sscore/sm : 1.  sm >= FLT_MIN when nz -> scale finite.
  if (tid < kS) {
    float ss = 0.f;
    for (int i = 0; i < 64; ++i) ss += prob_s[tid * 64 + i];
    float sm = ss * (1.f / 64.f);
    if (sm < 1.17549435e-38f) sm = 0.f;  // FTZ of the division result
    sscale[tid] = (sm != 0.f) ? (sscore[b * kS + tid] / sm) : 1.f;
  }
  __syncthreads();

  // pass 4: p2 = probs*scale (covered==1 everywhere); total = sum(p2)
  float p2[16];
  float lt = 0.f;
#pragma unroll
  for (int j = 0; j < 16; ++j) {
    const int t = tid + 256 * j;
    p2[j] = prob_s[t] * sscale[t >> 6];
    lt += p2[j];
  }
  float wt = lt;
#pragma unroll
  for (int off = 32; off >= 1; off >>= 1) wt += __shfl_xor(wt, off, 64);
  if (lane == 0) redt[wv] = wt;
  __syncthreads();
  const float total = (redt[0] + redt[1]) + (redt[2] + redt[3]);

#pragma unroll
  for (int j = 0; j < 16; ++j) {
    const int t = tid + 256 * j;
    out[(size_t)b * kT + t] = p2[j] / total;  // f32 division, like ref
  }
}

}  // namespace

extern "C" void kernel_launch(void* const* d_in, const int* in_sizes, int n_in,
                              void* d_out, int out_size, void* d_ws, size_t ws_size,
                              hipStream_t stream) {
  const float* doc    = (const float*)d_in[0];  // [B,T,D]
  const float* q      = (const float*)d_in[1];  // [B,TQ,D]
  const float* mask   = (const float*)d_in[2];  // [B,T]
  // d_in[3]: spans — deterministic [s*64, s*64+64), unused
  const float* sscore = (const float*)d_in[4];  // [B,S]
  float* out = (float*)d_out;                   // [B,T]

  // NO workspace use: scores staged in d_out itself (finish kernel does a
  // block-local read-then-overwrite of its own row).
  float* scores = out;

  score_kernel<<<(kB * kT) / 64, 512, 0, stream>>>(doc, q, scores);
  finish_kernel<<<kB, 256, 0, stream>>>(scores, mask, sscore, out);
}

// Round 7
// 38.206 us; speedup vs baseline: 1.0249x; 1.0249x over previous
//
#include <hip/hip_runtime.h>
#include <math.h>
#include <float.h>

namespace {

constexpr int kB  = 32;
constexpr int kT  = 4096;
constexpr int kTQ = 64;
constexpr int kD  = 256;
constexpr int kS  = 64;

// K0: qp[b,d] = max_tq q[b,tq,d]   (ws offsets 0..32KB proven safe r2/r4)
__global__ __launch_bounds__(256) void qpool_kernel(const float* __restrict__ q,
                                                    float* __restrict__ qp) {
  const int b = blockIdx.x;
  const int d = threadIdx.x;  // 256 == kD
  const float* base = q + (size_t)b * kTQ * kD + d;
  float m = base[0];
#pragma unroll
  for (int tq = 1; tq < kTQ; ++tq) m = fmaxf(m, base[tq * kD]);
  qp[b * kD + d] = m;
}

// K1: one block per span (2048 blocks, 256 thr = 4 waves x 16 tokens).
// Computes token scores (f32 products, f64-exact reduce), span max m_s and
// exp-sum se_s, writes P_t = mask ? exp(s_t - m_s) : 0 into out (staging),
// and (m_s, se_s) to the stats arrays in ws.
__global__ __launch_bounds__(256) void span_kernel(const float* __restrict__ doc,
                                                   const float* __restrict__ mask,
                                                   const float* __restrict__ qp,
                                                   float* __restrict__ P,
                                                   float* __restrict__ stm,
                                                   float* __restrict__ stse) {
  const int blk = blockIdx.x;  // b*kS + s
  const int b = blk >> 6;
  const int wave = threadIdx.x >> 6;
  const int lane = threadIdx.x & 63;
  const int t0 = blk * 64 + wave * 16;  // global token index (= b*kT + s*64 + ...)

  const float4 qv = reinterpret_cast<const float4*>(qp + b * kD)[lane];
  const float* dbase = doc + (size_t)t0 * kD + lane * 4;

  // 16 tokens per wave; token i's exact dot lands in lane i
  float myv = 0.f;
#pragma unroll
  for (int i = 0; i < 16; ++i) {
    const float4 dv = *reinterpret_cast<const float4*>(dbase + (size_t)i * kD);
    const float p0 = dv.x * qv.x;  // f32-rounded products (ref semantics)
    const float p1 = dv.y * qv.y;
    const float p2 = dv.z * qv.z;
    const float p3 = dv.w * qv.w;
    double s = ((double)p0 + (double)p1) + ((double)p2 + (double)p3);
#pragma unroll
    for (int off = 32; off >= 1; off >>= 1) s += __shfl_xor(s, off, 64);
    if (lane == i) myv = (float)s;
  }

  const float mk = (lane < 16) ? mask[t0 + lane] : 0.f;
  const float v = (mk != 0.f) ? myv : -INFINITY;

  // span max across wave (lanes >=16 are -inf), then across 4 waves
  float wm = v;
#pragma unroll
  for (int off = 32; off >= 1; off >>= 1) wm = fmaxf(wm, __shfl_xor(wm, off, 64));
  __shared__ float smax[4], ssum[4];
  if (lane == 0) smax[wave] = wm;
  __syncthreads();
  const float m_s = fmaxf(fmaxf(smax[0], smax[1]), fmaxf(smax[2], smax[3]));

  // e = exp(v - m_s) for unmasked, else 0 (guard fully-masked span: m_s=-inf)
  const float e = (v == -INFINITY) ? 0.f : expf(v - m_s);
  float ws = e;
#pragma unroll
  for (int off = 32; off >= 1; off >>= 1) ws += __shfl_xor(ws, off, 64);
  if (lane == 0) ssum[wave] = ws;
  __syncthreads();

  if (lane < 16) P[t0 + lane] = e;
  if (threadIdx.x == 0) {
    stm[blk] = m_s;
    stse[blk] = (ssum[0] + ssum[1]) + (ssum[2] + ssum[3]);
  }
}

// K2: per-batch finalize.  Wave 0 (64 lanes = 64 spans) reproduces the
// reference's FTZ-f32 dead-span semantics from span stats:
//   gmax = max m_s; denom = sum e^{m_s-gmax} se_s; logden = log(denom)
//   sm = e^{m_s-gmax-logden} * se_s / 64, FTZ -> dead if < FLT_MIN
//   alive: w_s = sscore_s / (se_s * SS_alive)   (global softmax cancels)
// Then all 256 threads rescale the row of P in place: out_t = P_t * w_s.
__global__ __launch_bounds__(256) void fin_kernel(const float* __restrict__ sscore,
                                                  const float* __restrict__ stm,
                                                  const float* __restrict__ stse,
                                                  float* __restrict__ out) {
  const int b = blockIdx.x;
  const int tid = threadIdx.x;
  __shared__ float wbuf[kS];

  if (tid < kS) {  // wave 0 only
    const float m = stm[b * kS + tid];
    const float se = stse[b * kS + tid];
    const bool mv = se > 0.f;  // span has >=1 unmasked token
    float g = mv ? m : -INFINITY;
#pragma unroll
    for (int off = 32; off >= 1; off >>= 1) g = fmaxf(g, __shfl_xor(g, off, 64));
    float contrib = mv ? expf(m - g) * se : 0.f;
    float den = contrib;
#pragma unroll
    for (int off = 32; off >= 1; off >>= 1) den += __shfl_xor(den, off, 64);
    const float logden = logf(den);

    const float t1 = mv ? expf((m - g) - logden) : 0.f;
    const float span_sum = t1 * se;
    const float sm = span_sum * (1.f / 64.f);
    const bool alive = mv && (sm >= FLT_MIN);  // subnormal/0 -> FTZ dead

    const float s0 = sscore[b * kS + tid];
    float ssv = alive ? s0 : 0.f;
#pragma unroll
    for (int off = 32; off >= 1; off >>= 1) ssv += __shfl_xor(ssv, off, 64);
    wbuf[tid] = alive ? s0 / (se * ssv) : 0.f;
  }
  __syncthreads();

  float* op = out + (size_t)b * kT;
#pragma unroll
  for (int j = 0; j < 4; ++j) {
    const int i4 = tid + 256 * j;  // float4 index in [0,1024)
    float4 p = reinterpret_cast<float4*>(op)[i4];
    const float w = wbuf[i4 >> 4];
    p.x *= w; p.y *= w; p.z *= w; p.w *= w;
    reinterpret_cast<float4*>(op)[i4] = p;
  }
}

}  // namespace

extern "C" void kernel_launch(void* const* d_in, const int* in_sizes, int n_in,
                              void* d_out, int out_size, void* d_ws, size_t ws_size,
                              hipStream_t stream) {
  const float* doc    = (const float*)d_in[0];  // [B,T,D]
  const float* q      = (const float*)d_in[1];  // [B,TQ,D]
  const float* mask   = (const float*)d_in[2];  // [B,T]
  // d_in[3]: spans — deterministic [s*64, s*64+64), unused
  const float* sscore = (const float*)d_in[4];  // [B,S]
  float* out = (float*)d_out;                   // [B,T]

  // ws layout (48 KB total; offsets <=40KB proven safe in r2/r4):
  float* qp   = (float*)d_ws;          // 32*256 = 32 KB
  float* stm  = qp + kB * kD;          // 2048 floats = 8 KB
  float* stse = stm + kB * kS;         // 2048 floats = 8 KB

  qpool_kernel<<<kB, kD, 0, stream>>>(q, qp);
  span_kernel<<<kB * kS, 256, 0, stream>>>(doc, mask, qp, out, stm, stse);
  fin_kernel<<<kB, 256, 0, stream>>>(sscore, stm, stse, out);
}

// Round 8
// 34.106 us; speedup vs baseline: 1.1481x; 1.1202x over previous
//
#include <hip/hip_runtime.h>
#include <math.h>
#include <float.h>

namespace {

constexpr int kB  = 32;
constexpr int kT  = 4096;
constexpr int kTQ = 64;
constexpr int kD  = 256;
constexpr int kS  = 64;

// K0: qp[b,d] = max_tq q[b,tq,d].  1024 threads: 4 tq-groups x 256 dims,
// depth-16 serial max per thread, LDS combine.
__global__ __launch_bounds__(1024) void qpool_kernel(const float* __restrict__ q,
                                                     float* __restrict__ qp) {
  const int b = blockIdx.x;
  const int tid = threadIdx.x;
  const int d = tid & 255;
  const int g = tid >> 8;  // 0..3
  const float* base = q + ((size_t)b * kTQ + g * 16) * kD + d;
  float m = base[0];
#pragma unroll
  for (int tq = 1; tq < 16; ++tq) m = fmaxf(m, base[tq * kD]);
  __shared__ float red[4][kD];
  red[g][d] = m;
  __syncthreads();
  if (g == 0) {
    qp[b * kD + d] = fmaxf(fmaxf(red[0][d], red[1][d]), fmaxf(red[2][d], red[3][d]));
  }
}

// K1: one block per span (2048 blocks, 256 thr = 4 waves x 16 tokens).
// Token scores: f32 products, f32 pairwise-tree + 6-step f32 butterfly.
// Writes P_t = mask ? exp(s_t - m_s) : 0 into out (staging) and (m_s, se_s)
// span stats to ws.
__global__ __launch_bounds__(256) void span_kernel(const float* __restrict__ doc,
                                                   const float* __restrict__ mask,
                                                   const float* __restrict__ qp,
                                                   float* __restrict__ P,
                                                   float* __restrict__ stm,
                                                   float* __restrict__ stse) {
  const int blk = blockIdx.x;  // b*kS + s
  const int b = blk >> 6;
  const int wave = threadIdx.x >> 6;
  const int lane = threadIdx.x & 63;
  const int t0 = blk * 64 + wave * 16;  // global token index

  const float4 qv = reinterpret_cast<const float4*>(qp + b * kD)[lane];
  const float* dbase = doc + (size_t)t0 * kD + lane * 4;

  // 16 tokens per wave; token i's dot lands in lane i (f32 tree reduce)
  float myv = 0.f;
#pragma unroll
  for (int i = 0; i < 16; ++i) {
    const float4 dv = *reinterpret_cast<const float4*>(dbase + (size_t)i * kD);
    float s = (dv.x * qv.x + dv.y * qv.y) + (dv.z * qv.z + dv.w * qv.w);
#pragma unroll
    for (int off = 32; off >= 1; off >>= 1) s += __shfl_xor(s, off, 64);
    if (lane == i) myv = s;
  }

  const float mk = (lane < 16) ? mask[t0 + lane] : 0.f;
  const float v = (mk != 0.f) ? myv : -INFINITY;

  // span max across wave (lanes >=16 are -inf), then across 4 waves
  float wm = v;
#pragma unroll
  for (int off = 32; off >= 1; off >>= 1) wm = fmaxf(wm, __shfl_xor(wm, off, 64));
  __shared__ float smax[4], ssum[4];
  if (lane == 0) smax[wave] = wm;
  __syncthreads();
  const float m_s = fmaxf(fmaxf(smax[0], smax[1]), fmaxf(smax[2], smax[3]));

  // e = exp(v - m_s) for unmasked, else 0 (guard fully-masked span: m_s=-inf)
  const float e = (v == -INFINITY) ? 0.f : expf(v - m_s);
  float ws = e;
#pragma unroll
  for (int off = 32; off >= 1; off >>= 1) ws += __shfl_xor(ws, off, 64);
  if (lane == 0) ssum[wave] = ws;
  __syncthreads();

  if (lane < 16) P[t0 + lane] = e;
  if (threadIdx.x == 0) {
    stm[blk] = m_s;
    stse[blk] = (ssum[0] + ssum[1]) + (ssum[2] + ssum[3]);
  }
}

// K2: finalize.  4 blocks per batch row; wave 0 of each block redundantly
// reproduces the FTZ-f32 dead-span semantics from span stats (cheap), then
// the block rescales its quarter of the row of P in place.
__global__ __launch_bounds__(256) void fin_kernel(const float* __restrict__ sscore,
                                                  const float* __restrict__ stm,
                                                  const float* __restrict__ stse,
                                                  float* __restrict__ out) {
  const int blk = blockIdx.x;
  const int b = blk >> 2;
  const int qtr = blk & 3;
  const int tid = threadIdx.x;
  __shared__ float wbuf[kS];

  if (tid < kS) {  // wave 0 only
    const float m = stm[b * kS + tid];
    const float se = stse[b * kS + tid];
    const bool mv = se > 0.f;  // span has >=1 unmasked token
    float g = mv ? m : -INFINITY;
#pragma unroll
    for (int off = 32; off >= 1; off >>= 1) g = fmaxf(g, __shfl_xor(g, off, 64));
    float contrib = mv ? expf(m - g) * se : 0.f;
    float den = contrib;
#pragma unroll
    for (int off = 32; off >= 1; off >>= 1) den += __shfl_xor(den, off, 64);
    const float logden = logf(den);

    const float t1 = mv ? expf((m - g) - logden) : 0.f;
    const float span_sum = t1 * se;
    const float sm = span_sum * (1.f / 64.f);
    const bool alive = mv && (sm >= FLT_MIN);  // subnormal/0 -> FTZ dead

    const float s0 = sscore[b * kS + tid];
    float ssv = alive ? s0 : 0.f;
#pragma unroll
    for (int off = 32; off >= 1; off >>= 1) ssv += __shfl_xor(ssv, off, 64);
    wbuf[tid] = alive ? s0 / (se * ssv) : 0.f;
  }
  __syncthreads();

  float* op = out + (size_t)b * kT;
  const int i4 = qtr * 256 + tid;  // float4 index in [0,1024)
  float4 p = reinterpret_cast<float4*>(op)[i4];
  const float w = wbuf[i4 >> 4];
  p.x *= w; p.y *= w; p.z *= w; p.w *= w;
  reinterpret_cast<float4*>(op)[i4] = p;
}

}  // namespace

extern "C" void kernel_launch(void* const* d_in, const int* in_sizes, int n_in,
                              void* d_out, int out_size, void* d_ws, size_t ws_size,
                              hipStream_t stream) {
  const float* doc    = (const float*)d_in[0];  // [B,T,D]
  const float* q      = (const float*)d_in[1];  // [B,TQ,D]
  const float* mask   = (const float*)d_in[2];  // [B,T]
  // d_in[3]: spans — deterministic [s*64, s*64+64), unused
  const float* sscore = (const float*)d_in[4];  // [B,S]
  float* out = (float*)d_out;                   // [B,T]

  // ws layout (ws is 512 MB — fills in rocprof showed the poison size):
  float* qp   = (float*)d_ws;          // 32*256 = 32 KB
  float* stm  = qp + kB * kD;          // 2048 floats = 8 KB
  float* stse = stm + kB * kS;         // 2048 floats = 8 KB

  qpool_kernel<<<kB, 1024, 0, stream>>>(q, qp);
  span_kernel<<<kB * kS, 256, 0, stream>>>(doc, mask, qp, out, stm, stse);
  fin_kernel<<<kB * 4, 256, 0, stream>>>(sscore, stm, stse, out);
}

// Round 9
// 32.821 us; speedup vs baseline: 1.1930x; 1.0392x over previous
//
#include <hip/hip_runtime.h>
#include <math.h>
#include <float.h>

namespace {

constexpr int kB  = 32;
constexpr int kT  = 4096;
constexpr int kTQ = 64;
constexpr int kD  = 256;
constexpr int kS  = 64;

// K0: qp[b,d] = max_tq q[b,tq,d].  128 blocks = (b, 64-dim group);
// 256 thr = 4 tq-quarters x 64 dims; depth-16 serial max + LDS combine.
__global__ __launch_bounds__(256) void qpool_kernel(const float* __restrict__ q,
                                                    float* __restrict__ qp) {
  const int blk = blockIdx.x;  // b*4 + dg
  const int b = blk >> 2;
  const int dg = blk & 3;
  const int tid = threadIdx.x;
  const int dd = tid & 63;
  const int g = tid >> 6;  // tq quarter (== wave)
  const int d = dg * 64 + dd;
  const float* base = q + ((size_t)b * kTQ + g * 16) * kD + d;
  float m = base[0];
#pragma unroll
  for (int tq = 1; tq < 16; ++tq) m = fmaxf(m, base[tq * kD]);
  __shared__ float red[4][64];
  red[g][dd] = m;
  __syncthreads();
  if (g == 0) {
    qp[b * kD + d] =
        fmaxf(fmaxf(red[0][dd], red[1][dd]), fmaxf(red[2][dd], red[3][dd]));
  }
}

// K1: one block per span (2048 blocks, 256 thr = 4 waves x 16 tokens).
// 4 lanes per token: lane owns dims {(l&3)*4 + 16k}; q segments preloaded
// from LDS into 16 float4 regs (broadcast ds_read_b128, conflict-free);
// dot finished by a 2-step shfl reduce.  Writes P_t = mask ? exp(s_t-m_s) : 0
// to out (staging) and (m_s, se_s) span stats to ws.
__global__ __launch_bounds__(256) void span_kernel(const float* __restrict__ doc,
                                                   const float* __restrict__ mask,
                                                   const float* __restrict__ qp,
                                                   float* __restrict__ P,
                                                   float* __restrict__ stm,
                                                   float* __restrict__ stse) {
  const int blk = blockIdx.x;  // b*kS + s
  const int b = blk >> 6;
  const int tid = threadIdx.x;
  const int wave = tid >> 6;
  const int lane = tid & 63;

  __shared__ float qpl[kD];
  qpl[tid] = qp[b * kD + tid];  // 256 threads == kD, coalesced 1 KB
  __syncthreads();

  // preload q segments for this lane: dims (lane&3)*4 + it*16
  float4 qv[16];
#pragma unroll
  for (int it = 0; it < 16; ++it) {
    qv[it] = *reinterpret_cast<const float4*>(&qpl[(lane & 3) * 4 + it * 16]);
  }

  const int myTok = lane >> 2;           // 0..15 within the wave's 16 tokens
  const int t0 = blk * 64 + wave * 16;   // global token base for this wave
  const float* dbase = doc + (size_t)(t0 + myTok) * kD + (lane & 3) * 4;

  // partial dot over this lane's 64 dims; 4 accumulators for ILP
  float a0 = 0.f, a1 = 0.f, a2 = 0.f, a3 = 0.f;
#pragma unroll
  for (int it = 0; it < 16; it += 4) {
    const float4 d0 = *reinterpret_cast<const float4*>(dbase + (it + 0) * 16);
    const float4 d1 = *reinterpret_cast<const float4*>(dbase + (it + 1) * 16);
    const float4 d2 = *reinterpret_cast<const float4*>(dbase + (it + 2) * 16);
    const float4 d3 = *reinterpret_cast<const float4*>(dbase + (it + 3) * 16);
    a0 += d0.x * qv[it + 0].x + d0.y * qv[it + 0].y + d0.z * qv[it + 0].z + d0.w * qv[it + 0].w;
    a1 += d1.x * qv[it + 1].x + d1.y * qv[it + 1].y + d1.z * qv[it + 1].z + d1.w * qv[it + 1].w;
    a2 += d2.x * qv[it + 2].x + d2.y * qv[it + 2].y + d2.z * qv[it + 2].z + d2.w * qv[it + 2].w;
    a3 += d3.x * qv[it + 3].x + d3.y * qv[it + 3].y + d3.z * qv[it + 3].z + d3.w * qv[it + 3].w;
  }
  float acc = (a0 + a1) + (a2 + a3);
  // finish the dot across the 4-lane group (result replicated in all 4 lanes)
  acc += __shfl_xor(acc, 1, 64);
  acc += __shfl_xor(acc, 2, 64);

  const float mk = mask[t0 + myTok];
  const float v = (mk != 0.f) ? acc : -INFINITY;

  // span max: butterfly over wave (values 4-replicated; max unaffected)
  float wm = v;
#pragma unroll
  for (int off = 32; off >= 1; off >>= 1) wm = fmaxf(wm, __shfl_xor(wm, off, 64));
  __shared__ float smax[4], ssum[4];
  if (lane == 0) smax[wave] = wm;
  __syncthreads();
  const float m_s = fmaxf(fmaxf(smax[0], smax[1]), fmaxf(smax[2], smax[3]));

  // e = exp(v - m_s) (0 for masked / fully-masked span); wave sum counts each
  // token 4x -> x0.25 is exact (pure power-of-two scaling).
  const float e = (v == -INFINITY) ? 0.f : expf(v - m_s);
  float ws = e;
#pragma unroll
  for (int off = 32; off >= 1; off >>= 1) ws += __shfl_xor(ws, off, 64);
  if (lane == 0) ssum[wave] = ws * 0.25f;
  __syncthreads();

  if ((lane & 3) == 0) P[t0 + myTok] = e;
  if (tid == 0) {
    stm[blk] = m_s;
    stse[blk] = (ssum[0] + ssum[1]) + (ssum[2] + ssum[3]);
  }
}

// K2: finalize.  4 blocks per batch row; wave 0 of each block redundantly
// reproduces the FTZ-f32 dead-span semantics from span stats (cheap), then
// the block rescales its quarter of the row of P in place.
__global__ __launch_bounds__(256) void fin_kernel(const float* __restrict__ sscore,
                                                  const float* __restrict__ stm,
                                                  const float* __restrict__ stse,
                                                  float* __restrict__ out) {
  const int blk = blockIdx.x;
  const int b = blk >> 2;
  const int qtr = blk & 3;
  const int tid = threadIdx.x;
  __shared__ float wbuf[kS];

  if (tid < kS) {  // wave 0 only
    const float m = stm[b * kS + tid];
    const float se = stse[b * kS + tid];
    const bool mv = se > 0.f;  // span has >=1 unmasked token
    float g = mv ? m : -INFINITY;
#pragma unroll
    for (int off = 32; off >= 1; off >>= 1) g = fmaxf(g, __shfl_xor(g, off, 64));
    float contrib = mv ? expf(m - g) * se : 0.f;
    float den = contrib;
#pragma unroll
    for (int off = 32; off >= 1; off >>= 1) den += __shfl_xor(den, off, 64);
    const float logden = logf(den);

    const float t1 = mv ? expf((m - g) - logden) : 0.f;
    const float span_sum = t1 * se;
    const float sm = span_sum * (1.f / 64.f);
    const bool alive = mv && (sm >= FLT_MIN);  // subnormal/0 -> FTZ dead

    const float s0 = sscore[b * kS + tid];
    float ssv = alive ? s0 : 0.f;
#pragma unroll
    for (int off = 32; off >= 1; off >>= 1) ssv += __shfl_xor(ssv, off, 64);
    wbuf[tid] = alive ? s0 / (se * ssv) : 0.f;
  }
  __syncthreads();

  float* op = out + (size_t)b * kT;
  const int i4 = qtr * 256 + tid;  // float4 index in [0,1024)
  float4 p = reinterpret_cast<float4*>(op)[i4];
  const float w = wbuf[i4 >> 4];
  p.x *= w; p.y *= w; p.z *= w; p.w *= w;
  reinterpret_cast<float4*>(op)[i4] = p;
}

}  // namespace

extern "C" void kernel_launch(void* const* d_in, const int* in_sizes, int n_in,
                              void* d_out, int out_size, void* d_ws, size_t ws_size,
                              hipStream_t stream) {
  const float* doc    = (const float*)d_in[0];  // [B,T,D]
  const float* q      = (const float*)d_in[1];  // [B,TQ,D]
  const float* mask   = (const float*)d_in[2];  // [B,T]
  // d_in[3]: spans — deterministic [s*64, s*64+64), unused
  const float* sscore = (const float*)d_in[4];  // [B,S]
  float* out = (float*)d_out;                   // [B,T]

  float* qp   = (float*)d_ws;   // 32*256 = 32 KB
  float* stm  = qp + kB * kD;   // 2048 floats = 8 KB
  float* stse = stm + kB * kS;  // 2048 floats = 8 KB

  qpool_kernel<<<kB * 4, 256, 0, stream>>>(q, qp);
  span_kernel<<<kB * kS, 256, 0, stream>>>(doc, mask, qp, out, stm, stse);
  fin_kernel<<<kB * 4, 256, 0, stream>>>(sscore, stm, stse, out);
}